// Round 5
// baseline (353.263 us; speedup 1.0000x reference)
//
#include <hip/hip_runtime.h>
#include <hip/hip_bf16.h>

#define MASK_ID 3
#define MAX_SEN 128
#define NB 8
#define SEQ 8192
#define EMB 1024
#define DIM 128

typedef __attribute__((ext_vector_type(8))) short short8v;   // 8 bf16
typedef __attribute__((ext_vector_type(4))) float f32x4;     // MFMA accumulator

#define MFMA(a, b, c) __builtin_amdgcn_mfma_f32_16x16x32_bf16(a, b, c, 0, 0, 0)

// fp32 -> bf16 (round-nearest-even), raw short
__device__ __forceinline__ short f2b(float x) {
    union { float f; unsigned u; } v; v.f = x;
    unsigned r = (v.u + 0x7FFFu + ((v.u >> 16) & 1u)) >> 16;
    return (short)r;
}

__device__ __forceinline__ short8v cvt8(float4 a, float4 b) {
    short8v r;
    r[0] = f2b(a.x); r[1] = f2b(a.y); r[2] = f2b(a.z); r[3] = f2b(a.w);
    r[4] = f2b(b.x); r[5] = f2b(b.y); r[6] = f2b(b.z); r[7] = f2b(b.w);
    return r;
}

// ---------------- Kernel 1: per-row scan -> mask positions + nvis ----------------
__global__ __launch_bounds__(1024) void seg_kernel(const int* __restrict__ ids,
                                                   int* __restrict__ pos,
                                                   int* __restrict__ nvis) {
    int b = blockIdx.x;
    int tid = threadIdx.x;
    __shared__ int sc[1024];
    __shared__ int sc2[1024];
    const int PER = SEQ / 1024;  // 8
    int base = b * SEQ + tid * PER;

    int ids_l[PER];
    int cnt = 0;
    #pragma unroll
    for (int j = 0; j < PER; j++) {
        ids_l[j] = ids[base + j];
        cnt += (ids_l[j] == MASK_ID) ? 1 : 0;
    }
    if (tid < MAX_SEN) pos[b * MAX_SEN + tid] = -1;
    sc[tid] = cnt;
    __syncthreads();

    int* src = sc;
    int* dst = sc2;
    for (int off = 1; off < 1024; off <<= 1) {
        int v = src[tid];
        if (tid >= off) v += src[tid - off];
        dst[tid] = v;
        __syncthreads();
        int* t = src; src = dst; dst = t;
    }
    int incl = src[tid];
    int run = incl - cnt;  // exclusive prefix

    #pragma unroll
    for (int j = 0; j < PER; j++) {
        if (ids_l[j] == MASK_ID) {
            run++;
            if (run <= MAX_SEN) pos[b * MAX_SEN + run - 1] = tid * PER + j;
        }
        int nv = run; if (nv > MAX_SEN) nv = MAX_SEN;
        nvis[base + j] = nv;
    }
}

// ---------------- Kernel 2: transpose+convert weights to bf16 ----------------
__global__ __launch_bounds__(256) void prep_w(const float* __restrict__ Wq,
                                              const float* __restrict__ Wo,
                                              short* __restrict__ WqT,
                                              short* __restrict__ WoT) {
    int idx = blockIdx.x * 256 + threadIdx.x;      // 0 .. 131071
    int d = idx >> 10, e = idx & 1023;
    WqT[idx] = f2b(Wq[e * DIM + d]);
    int e2 = idx >> 7, d2 = idx & 127;
    WoT[idx] = f2b(Wo[d2 * EMB + e2]);
}

// ---------------- Kernel 3: fused static+kv: k_bf[m][d], vT_bf[d][m] ----------------
__global__ __launch_bounds__(128) void statkv_kernel(const float* __restrict__ hidden,
                                                     const float* __restrict__ Wv, const float* __restrict__ bv,
                                                     const float* __restrict__ Wk, const float* __restrict__ bk,
                                                     const float* __restrict__ Wvt, const float* __restrict__ bvt,
                                                     const int* __restrict__ pos,
                                                     short* __restrict__ k_bf, short* __restrict__ vT_bf) {
    int m = blockIdx.x, b = blockIdx.y;
    int d = threadIdx.x;
    __shared__ float h[EMB];
    __shared__ float srow[DIM];
    int p = pos[b * MAX_SEN + m];   // uniform across block
    float acc = bv[d];
    if (p >= 0) {
        const float* hp = hidden + ((size_t)b * SEQ + p) * EMB;
        for (int e = d; e < EMB; e += 128) h[e] = hp[e];
        __syncthreads();
        float a0 = 0.f, a1 = 0.f, a2 = 0.f, a3 = 0.f;
        for (int e = 0; e < EMB; e += 4) {
            a0 += h[e]     * Wv[e * DIM + d];
            a1 += h[e + 1] * Wv[(e + 1) * DIM + d];
            a2 += h[e + 2] * Wv[(e + 2) * DIM + d];
            a3 += h[e + 3] * Wv[(e + 3) * DIM + d];
        }
        acc += (a0 + a1) + (a2 + a3);
    }
    srow[d] = acc;
    __syncthreads();
    float k0 = 0.f, k1 = 0.f, v0 = 0.f, v1 = 0.f;
    for (int e = 0; e < DIM; e += 2) {
        float s0 = srow[e], s1 = srow[e + 1];
        k0 += s0 * Wk[e * DIM + d];
        k1 += s1 * Wk[(e + 1) * DIM + d];
        v0 += s0 * Wvt[e * DIM + d];
        v1 += s1 * Wvt[(e + 1) * DIM + d];
    }
    k_bf[((size_t)b * MAX_SEN + m) * DIM + d] = f2b(bk[d] + k0 + k1);
    vT_bf[((size_t)b * DIM + d) * MAX_SEN + m] = f2b(bvt[d] + v0 + v1);
}

// ---------------- Kernel 4: fused MFMA attention per 32-token tile ----------------
// Phase 1 is barrier-free: hidden A-fragments and WqT B-fragments load straight
// from global into regs (natural MFMA layout), so the compiler can pipeline the
// HBM stream with no vmcnt(0) drains. LDS only for the genuine transposes.
__global__ __launch_bounds__(256, 4) void attn_kernel(
    const float* __restrict__ hidden,
    const short* __restrict__ WqT, const float* __restrict__ bq,
    const short* __restrict__ k_bf, const short* __restrict__ vT_bf,
    const short* __restrict__ WoT, const float* __restrict__ bo,
    const int* __restrict__ nvis,
    float* __restrict__ out) {
    int blk = blockIdx.x;
    int b  = blk >> 8;             // 256 tiles per batch
    int s0 = (blk & 255) * 32;
    int tid = threadIdx.x;
    int lane = tid & 63;
    int w  = tid >> 6;             // wave 0..3
    int lr = lane & 15;
    int lq = lane >> 4;            // quarter 0..3

    // LDS: [0,16896) = lg fp32 (stride 132); after softmax reads complete,
    // the same region hosts pP (at +0, 8KB) and odB (at +8448, 8KB).
    // [16896, 25088) = qP (32 rows x 256B, swizzled).
    __shared__ __align__(16) char SH[25088];
    float* lg  = (float*)SH;
    char*  pPc = SH;
    char*  odc = SH + 8448;
    char*  qPc = SH + 16896;

    const size_t hrow = (size_t)b * SEQ + s0;
    const float* hbase = hidden + hrow * EMB;
    f32x4 zero = {0.f, 0.f, 0.f, 0.f};

    // ================= phase 1: q = (H @ Wq + bq) * scale  (NO LDS, NO barriers) =================
    f32x4 a00 = zero, a01 = zero, a10 = zero, a11 = zero;
    {
        const short* wq0 = WqT + (size_t)(w * 32 + lr) * 1024 + lq * 8;
        const short* wq1 = wq0 + 16 * 1024;
        const float* h0 = hbase + (size_t)lr * EMB + lq * 8;
        const float* h1 = h0 + 16 * EMB;
        #pragma unroll 2
        for (int c = 0; c < 8; c++) {
            #pragma unroll
            for (int kk = 0; kk < 4; kk++) {
                int off = c * 128 + kk * 32;
                float4 x0 = *(const float4*)(h0 + off);
                float4 x1 = *(const float4*)(h0 + off + 4);
                float4 y0 = *(const float4*)(h1 + off);
                float4 y1 = *(const float4*)(h1 + off + 4);
                short8v fa0 = cvt8(x0, x1);
                short8v fa1 = cvt8(y0, y1);
                const short8v fb0 = *(const short8v*)(wq0 + off);
                const short8v fb1 = *(const short8v*)(wq1 + off);
                a00 = MFMA(fa0, fb0, a00); a01 = MFMA(fa0, fb1, a01);
                a10 = MFMA(fa1, fb0, a10); a11 = MFMA(fa1, fb1, a11);
            }
        }
    }
    {
        const float scale = 0.08838834764831845f;  // 128^-0.5
        int d0 = w * 32 + lr;
        float bq0 = bq[d0], bq1 = bq[d0 + 16];
        #pragma unroll
        for (int r = 0; r < 4; r++) {
            int r0 = lq * 4 + r, r1 = 16 + r0;
            *(short*)(qPc + ((r0 * 256 + d0 * 2) ^ ((r0 & 7) << 4)))        = f2b((a00[r] + bq0) * scale);
            *(short*)(qPc + ((r0 * 256 + (d0 + 16) * 2) ^ ((r0 & 7) << 4))) = f2b((a01[r] + bq1) * scale);
            *(short*)(qPc + ((r1 * 256 + d0 * 2) ^ ((r1 & 7) << 4)))        = f2b((a10[r] + bq0) * scale);
            *(short*)(qPc + ((r1 * 256 + (d0 + 16) * 2) ^ ((r1 & 7) << 4))) = f2b((a11[r] + bq1) * scale);
        }
    }
    __syncthreads();   // B1: q visible

    // ================= phase 2: logits = q @ K^T =================
    {
        f32x4 l00 = zero, l01 = zero, l10 = zero, l11 = zero;
        const short* kbp0 = k_bf + ((size_t)b << 14) + (w * 32 + lr) * 128 + lq * 8;
        const short* kbp1 = kbp0 + 16 * 128;
        #pragma unroll
        for (int kk = 0; kk < 4; kk++) {
            short8v fa0 = *(short8v*)(qPc + ((lr * 256 + kk * 64 + lq * 16) ^ ((lr & 7) << 4)));
            short8v fa1 = *(short8v*)(qPc + (((16 + lr) * 256 + kk * 64 + lq * 16) ^ ((lr & 7) << 4)));
            short8v fb0 = *(const short8v*)(kbp0 + kk * 32);
            short8v fb1 = *(const short8v*)(kbp1 + kk * 32);
            l00 = MFMA(fa0, fb0, l00); l01 = MFMA(fa0, fb1, l01);
            l10 = MFMA(fa1, fb0, l10); l11 = MFMA(fa1, fb1, l11);
        }
        int m0 = w * 32 + lr;
        #pragma unroll
        for (int r = 0; r < 4; r++) {
            int r0 = lq * 4 + r, r1 = 16 + r0;
            lg[r0 * 132 + m0]      = l00[r];
            lg[r0 * 132 + m0 + 16] = l01[r];
            lg[r1 * 132 + m0]      = l10[r];
            lg[r1 * 132 + m0 + 16] = l11[r];
        }
    }
    __syncthreads();   // B2: logits visible

    // ================= phase 3: masked softmax (8 threads/token, all in regs) =================
    {
        int t = tid >> 3, sub = tid & 7;
        int nv = nvis[b * SEQ + s0 + t];
        const float* lrow = lg + t * 132 + sub * 16;
        float pv[16];
        {
            float4 v0 = *(const float4*)(lrow + 0);
            float4 v1 = *(const float4*)(lrow + 4);
            float4 v2 = *(const float4*)(lrow + 8);
            float4 v3 = *(const float4*)(lrow + 12);
            pv[0] = v0.x; pv[1] = v0.y; pv[2]  = v0.z; pv[3]  = v0.w;
            pv[4] = v1.x; pv[5] = v1.y; pv[6]  = v1.z; pv[7]  = v1.w;
            pv[8] = v2.x; pv[9] = v2.y; pv[10] = v2.z; pv[11] = v2.w;
            pv[12] = v3.x; pv[13] = v3.y; pv[14] = v3.z; pv[15] = v3.w;
        }
        int base_m = sub * 16;
        float mx = -3.0e38f;
        #pragma unroll
        for (int i = 0; i < 16; i++)
            mx = (base_m + i < nv) ? fmaxf(mx, pv[i]) : mx;
        mx = fmaxf(mx, __shfl_xor(mx, 1));
        mx = fmaxf(mx, __shfl_xor(mx, 2));
        mx = fmaxf(mx, __shfl_xor(mx, 4));
        float sum = 0.f;
        #pragma unroll
        for (int i = 0; i < 16; i++) {
            float e = (base_m + i < nv) ? __expf(pv[i] - mx) : 0.f;
            pv[i] = e;
            sum += e;
        }
        sum += __shfl_xor(sum, 1);
        sum += __shfl_xor(sum, 2);
        sum += __shfl_xor(sum, 4);
        float inv = (nv > 0) ? 1.0f / sum : 0.f;

        __syncthreads();   // B3: all lg reads done; safe to overwrite with pP

        short8v p0, p1;
        #pragma unroll
        for (int i = 0; i < 8; i++) { p0[i] = f2b(pv[i] * inv); p1[i] = f2b(pv[8 + i] * inv); }
        int base = t * 256 + sub * 32;
        int x = (t & 7) << 4;
        *(short8v*)(pPc + (base ^ x))        = p0;
        *(short8v*)(pPc + ((base + 16) ^ x)) = p1;
    }
    __syncthreads();   // B4: P visible

    // ================= phase 4: od = P @ V =================
    {
        f32x4 o00 = zero, o01 = zero, o10 = zero, o11 = zero;
        const short* vbp0 = vT_bf + ((size_t)b << 14) + (w * 32 + lr) * 128 + lq * 8;
        const short* vbp1 = vbp0 + 16 * 128;
        #pragma unroll
        for (int kk = 0; kk < 4; kk++) {
            short8v fa0 = *(short8v*)(pPc + ((lr * 256 + kk * 64 + lq * 16) ^ ((lr & 7) << 4)));
            short8v fa1 = *(short8v*)(pPc + (((16 + lr) * 256 + kk * 64 + lq * 16) ^ ((lr & 7) << 4)));
            short8v fb0 = *(const short8v*)(vbp0 + kk * 32);
            short8v fb1 = *(const short8v*)(vbp1 + kk * 32);
            o00 = MFMA(fa0, fb0, o00); o01 = MFMA(fa0, fb1, o01);
            o10 = MFMA(fa1, fb0, o10); o11 = MFMA(fa1, fb1, o11);
        }
        int d0 = w * 32 + lr;
        #pragma unroll
        for (int r = 0; r < 4; r++) {
            int r0 = lq * 4 + r, r1 = 16 + r0;
            *(short*)(odc + ((r0 * 256 + d0 * 2) ^ ((r0 & 7) << 4)))        = f2b(o00[r]);
            *(short*)(odc + ((r0 * 256 + (d0 + 16) * 2) ^ ((r0 & 7) << 4))) = f2b(o01[r]);
            *(short*)(odc + ((r1 * 256 + d0 * 2) ^ ((r1 & 7) << 4)))        = f2b(o10[r]);
            *(short*)(odc + ((r1 * 256 + (d0 + 16) * 2) ^ ((r1 & 7) << 4))) = f2b(o11[r]);
        }
    }
    __syncthreads();   // B5: od visible

    // ================= phase 5: out = od @ Wo + bo  (wave w -> col quarter w) =================
    {
        short8v af0[4], af1[4];
        #pragma unroll
        for (int kk = 0; kk < 4; kk++) {
            af0[kk] = *(short8v*)(odc + ((lr * 256 + kk * 64 + lq * 16) ^ ((lr & 7) << 4)));
            af1[kk] = *(short8v*)(odc + (((16 + lr) * 256 + kk * 64 + lq * 16) ^ ((lr & 7) << 4)));
        }
        #pragma unroll
        for (int pass = 0; pass < 4; pass++) {
            int ep = w * 256 + pass * 64;
            f32x4 ac0[4], ac1[4];
            #pragma unroll
            for (int e2 = 0; e2 < 4; e2++) { ac0[e2] = zero; ac1[e2] = zero; }
            #pragma unroll
            for (int kk = 0; kk < 4; kk++) {
                #pragma unroll
                for (int e2 = 0; e2 < 4; e2++) {
                    const short8v bb = *(const short8v*)(WoT + (size_t)(ep + e2 * 16 + lr) * 128
                                                         + kk * 32 + lq * 8);
                    ac0[e2] = MFMA(af0[kk], bb, ac0[e2]);
                    ac1[e2] = MFMA(af1[kk], bb, ac1[e2]);
                }
            }
            #pragma unroll
            for (int e2 = 0; e2 < 4; e2++) {
                int col = ep + e2 * 16 + lr;
                float bov = bo[col];
                #pragma unroll
                for (int r = 0; r < 4; r++) {
                    out[(hrow + lq * 4 + r) * EMB + col]      = ac0[e2][r] + bov;
                    out[(hrow + 16 + lq * 4 + r) * EMB + col] = ac1[e2][r] + bov;
                }
            }
        }
    }
}

extern "C" void kernel_launch(void* const* d_in, const int* in_sizes, int n_in,
                              void* d_out, int out_size, void* d_ws, size_t ws_size,
                              hipStream_t stream) {
    const int*   ids    = (const int*)d_in[0];
    const float* hidden = (const float*)d_in[1];
    const float* Wv     = (const float*)d_in[2];
    const float* bv     = (const float*)d_in[3];
    const float* Wq     = (const float*)d_in[4];
    const float* bq     = (const float*)d_in[5];
    const float* Wk     = (const float*)d_in[6];
    const float* bk     = (const float*)d_in[7];
    const float* Wvt    = (const float*)d_in[8];
    const float* bvt    = (const float*)d_in[9];
    const float* Wo     = (const float*)d_in[10];
    const float* bo     = (const float*)d_in[11];

    char* ws = (char*)d_ws;
    int*   pos   = (int*)ws;                                   // 4 KB
    int*   nvis  = (int*)(ws + (4 << 10));                     // 256 KB
    short* k_bf  = (short*)(ws + (260 << 10));                 // 256 KB
    short* vT_bf = (short*)(ws + (516 << 10));                 // 256 KB
    short* WqT   = (short*)(ws + (772 << 10));                 // 256 KB
    short* WoT   = (short*)(ws + (1028 << 10));                // 256 KB (total 1284 KB)

    seg_kernel<<<NB, 1024, 0, stream>>>(ids, pos, nvis);
    prep_w<<<512, 256, 0, stream>>>(Wq, Wo, WqT, WoT);
    dim3 g2(MAX_SEN, NB);
    statkv_kernel<<<g2, 128, 0, stream>>>(hidden, Wv, bv, Wk, bk, Wvt, bvt, pos, k_bf, vT_bf);
    attn_kernel<<<NB * (SEQ / 32), 256, 0, stream>>>(hidden, WqT, bq, k_bf, vT_bf, WoT, bo,
                                                     nvis, (float*)d_out);
}

// Round 6
// 261.849 us; speedup vs baseline: 1.3491x; 1.3491x over previous
//
#include <hip/hip_runtime.h>
#include <hip/hip_bf16.h>

#define MASK_ID 3
#define MAX_SEN 128
#define NB 8
#define SEQ 8192
#define EMB 1024
#define DIM 128

typedef __attribute__((ext_vector_type(8))) short short8v;   // 8 bf16
typedef __attribute__((ext_vector_type(4))) float f32x4;     // MFMA accumulator

#define MFMA(a, b, c) __builtin_amdgcn_mfma_f32_16x16x32_bf16(a, b, c, 0, 0, 0)

typedef __attribute__((address_space(1))) const void g_void;
typedef __attribute__((address_space(3))) void l_void;

// fp32 -> bf16 (round-nearest-even), raw short
__device__ __forceinline__ short f2b(float x) {
    union { float f; unsigned u; } v; v.f = x;
    unsigned r = (v.u + 0x7FFFu + ((v.u >> 16) & 1u)) >> 16;
    return (short)r;
}

__device__ __forceinline__ short8v cvt8(float4 a, float4 b) {
    short8v r;
    r[0] = f2b(a.x); r[1] = f2b(a.y); r[2] = f2b(a.z); r[3] = f2b(a.w);
    r[4] = f2b(b.x); r[5] = f2b(b.y); r[6] = f2b(b.z); r[7] = f2b(b.w);
    return r;
}

// ---------------- Kernel 1: per-row scan -> mask positions + nvis ----------------
__global__ __launch_bounds__(1024) void seg_kernel(const int* __restrict__ ids,
                                                   int* __restrict__ pos,
                                                   int* __restrict__ nvis) {
    int b = blockIdx.x;
    int tid = threadIdx.x;
    __shared__ int sc[1024];
    __shared__ int sc2[1024];
    const int PER = SEQ / 1024;  // 8
    int base = b * SEQ + tid * PER;

    int ids_l[PER];
    int cnt = 0;
    #pragma unroll
    for (int j = 0; j < PER; j++) {
        ids_l[j] = ids[base + j];
        cnt += (ids_l[j] == MASK_ID) ? 1 : 0;
    }
    if (tid < MAX_SEN) pos[b * MAX_SEN + tid] = -1;
    sc[tid] = cnt;
    __syncthreads();

    int* src = sc;
    int* dst = sc2;
    for (int off = 1; off < 1024; off <<= 1) {
        int v = src[tid];
        if (tid >= off) v += src[tid - off];
        dst[tid] = v;
        __syncthreads();
        int* t = src; src = dst; dst = t;
    }
    int incl = src[tid];
    int run = incl - cnt;  // exclusive prefix

    #pragma unroll
    for (int j = 0; j < PER; j++) {
        if (ids_l[j] == MASK_ID) {
            run++;
            if (run <= MAX_SEN) pos[b * MAX_SEN + run - 1] = tid * PER + j;
        }
        int nv = run; if (nv > MAX_SEN) nv = MAX_SEN;
        nvis[base + j] = nv;
    }
}

// ---------------- Kernel 2: transpose+convert weights to bf16 ----------------
__global__ __launch_bounds__(256) void prep_w(const float* __restrict__ Wq,
                                              const float* __restrict__ Wo,
                                              short* __restrict__ WqT,
                                              short* __restrict__ WoT) {
    int idx = blockIdx.x * 256 + threadIdx.x;      // 0 .. 131071
    int d = idx >> 10, e = idx & 1023;
    WqT[idx] = f2b(Wq[e * DIM + d]);
    int e2 = idx >> 7, d2 = idx & 127;
    WoT[idx] = f2b(Wo[d2 * EMB + e2]);
}

// ---------------- Kernel 3: fused static+kv: k_bf[m][d], vT_bf[d][m] ----------------
__global__ __launch_bounds__(128) void statkv_kernel(const float* __restrict__ hidden,
                                                     const float* __restrict__ Wv, const float* __restrict__ bv,
                                                     const float* __restrict__ Wk, const float* __restrict__ bk,
                                                     const float* __restrict__ Wvt, const float* __restrict__ bvt,
                                                     const int* __restrict__ pos,
                                                     short* __restrict__ k_bf, short* __restrict__ vT_bf) {
    int m = blockIdx.x, b = blockIdx.y;
    int d = threadIdx.x;
    __shared__ float h[EMB];
    __shared__ float srow[DIM];
    int p = pos[b * MAX_SEN + m];   // uniform across block
    float acc = bv[d];
    if (p >= 0) {
        const float* hp = hidden + ((size_t)b * SEQ + p) * EMB;
        for (int e = d; e < EMB; e += 128) h[e] = hp[e];
        __syncthreads();
        float a0 = 0.f, a1 = 0.f, a2 = 0.f, a3 = 0.f;
        for (int e = 0; e < EMB; e += 4) {
            a0 += h[e]     * Wv[e * DIM + d];
            a1 += h[e + 1] * Wv[(e + 1) * DIM + d];
            a2 += h[e + 2] * Wv[(e + 2) * DIM + d];
            a3 += h[e + 3] * Wv[(e + 3) * DIM + d];
        }
        acc += (a0 + a1) + (a2 + a3);
    }
    srow[d] = acc;
    __syncthreads();
    float k0 = 0.f, k1 = 0.f, v0 = 0.f, v1 = 0.f;
    for (int e = 0; e < DIM; e += 2) {
        float s0 = srow[e], s1 = srow[e + 1];
        k0 += s0 * Wk[e * DIM + d];
        k1 += s1 * Wk[(e + 1) * DIM + d];
        v0 += s0 * Wvt[e * DIM + d];
        v1 += s1 * Wvt[(e + 1) * DIM + d];
    }
    k_bf[((size_t)b * MAX_SEN + m) * DIM + d] = f2b(bk[d] + k0 + k1);
    vT_bf[((size_t)b * DIM + d) * MAX_SEN + m] = f2b(bvt[d] + v0 + v1);
}

// ---------------- Kernel 4: fused MFMA attention, 64 tokens/block ----------------
// Phase 1 stages hidden (fp32) via global_load_lds width=16 with pre-swizzled
// global source (rule #21: linear LDS dest + inverse-swz source + swz read).
// Per-iteration: barrier(drain chunk c) -> issue glds(c+1) -> compute(c), so
// chunk c+1's HBM latency hides under chunk c's ds_read/cvt/MFMA.
__global__ __launch_bounds__(256, 3) void attn_kernel(
    const float* __restrict__ hidden,
    const short* __restrict__ WqT, const float* __restrict__ bq,
    const short* __restrict__ k_bf, const short* __restrict__ vT_bf,
    const short* __restrict__ WoT, const float* __restrict__ bo,
    const int* __restrict__ nvis,
    float* __restrict__ out) {
    // XCD swizzle: 1024 blocks = 8 XCDs x 128; XCD x owns batch x (K/V L2-resident)
    int wg = (blockIdx.x & 7) * 128 + (blockIdx.x >> 3);
    int b  = wg >> 7;
    int s0 = (wg & 127) * 64;
    int tid = threadIdx.x;
    int lane = tid & 63;
    int w  = tid >> 6;             // wave 0..3
    int lr = lane & 15;
    int lq = lane >> 4;            // quarter 0..3

    // LDS 48KB: [0,32K) = A-dbuf (2x16K) -> lg (64x512B swz) -> pP[0,16K)+od[16K,32K)
    //           [32K,48K) = qP (64 rows x 256B, swz)
    __shared__ __align__(16) char SH[49152];
    char* Abuf0 = SH;
    char* Abuf1 = SH + 16384;
    char* pPc   = SH;
    char* odc   = SH + 16384;
    char* qPc   = SH + 32768;

    const size_t hrow = (size_t)b * SEQ + s0;
    const char* hbytes = (const char*)(hidden + hrow * EMB);
    f32x4 zero = {0.f, 0.f, 0.f, 0.f};

    // ================= phase 1: q = (H @ Wq + bq) * scale =================
    f32x4 acc[4][2];
    #pragma unroll
    for (int rf = 0; rf < 4; rf++) { acc[rf][0] = zero; acc[rf][1] = zero; }

    // prologue: stage chunk 0
    {
        int lsub = lane >> 4;
        int blin = (lane & 15) << 4;
        #pragma unroll
        for (int j = 0; j < 4; j++) {
            int row = w * 16 + j * 4 + lsub;
            const char* src = hbytes + (size_t)row * 4096 + (blin ^ ((row & 7) << 4));
            __builtin_amdgcn_global_load_lds((g_void*)src,
                                             (l_void*)(Abuf0 + w * 4096 + j * 1024),
                                             16, 0, 0);
        }
    }

    char* bcur = Abuf0;
    char* bnext = Abuf1;
    for (int c = 0; c < 16; c++) {
        __syncthreads();           // drains vmcnt -> chunk c resident; syncs dbuf WAR
        if (c < 15) {
            int lsub = lane >> 4;
            int blin = (lane & 15) << 4;
            #pragma unroll
            for (int j = 0; j < 4; j++) {
                int row = w * 16 + j * 4 + lsub;
                const char* src = hbytes + (size_t)row * 4096 + (c + 1) * 256
                                  + (blin ^ ((row & 7) << 4));
                __builtin_amdgcn_global_load_lds((g_void*)src,
                                                 (l_void*)(bnext + w * 4096 + j * 1024),
                                                 16, 0, 0);
            }
        }
        // compute chunk c (BK=64 -> 2 k-steps)
        #pragma unroll
        for (int ks = 0; ks < 2; ks++) {
            const short8v fb0 = *(const short8v*)(WqT + (size_t)(w * 32 + lr) * 1024
                                                  + c * 64 + ks * 32 + lq * 8);
            const short8v fb1 = *(const short8v*)(WqT + (size_t)(w * 32 + 16 + lr) * 1024
                                                  + c * 64 + ks * 32 + lq * 8);
            #pragma unroll
            for (int rf = 0; rf < 4; rf++) {
                int row = rf * 16 + lr;
                int x = (row & 7) << 4;
                int kb = ks * 128 + lq * 32;
                float4 f0 = *(const float4*)(bcur + row * 256 + (kb ^ x));
                float4 f1 = *(const float4*)(bcur + row * 256 + ((kb + 16) ^ x));
                short8v fa = cvt8(f0, f1);
                acc[rf][0] = MFMA(fa, fb0, acc[rf][0]);
                acc[rf][1] = MFMA(fa, fb1, acc[rf][1]);
            }
        }
        char* t = bcur; bcur = bnext; bnext = t;
    }
    {
        const float scale = 0.08838834764831845f;  // 128^-0.5
        int d0 = w * 32 + lr;
        float bq0 = bq[d0], bq1 = bq[d0 + 16];
        #pragma unroll
        for (int rf = 0; rf < 4; rf++)
            #pragma unroll
            for (int r = 0; r < 4; r++) {
                int row = rf * 16 + lq * 4 + r;
                int x = (row & 7) << 4;
                *(short*)(qPc + row * 256 + ((d0 * 2) ^ x))        = f2b((acc[rf][0][r] + bq0) * scale);
                *(short*)(qPc + row * 256 + (((d0 + 16) * 2) ^ x)) = f2b((acc[rf][1][r] + bq1) * scale);
            }
    }
    __syncthreads();   // B1: q visible; Abuf dead -> lg region live

    // ================= phase 2: logits = q @ K^T (lg = 64 rows x 512B, swz) =================
    {
        f32x4 l[4][2];
        #pragma unroll
        for (int rf = 0; rf < 4; rf++) { l[rf][0] = zero; l[rf][1] = zero; }
        const short* kb0 = k_bf + ((size_t)b << 14) + (w * 32 + lr) * 128 + lq * 8;
        const short* kb1 = kb0 + 16 * 128;
        #pragma unroll
        for (int kk = 0; kk < 4; kk++) {
            const short8v fb0 = *(const short8v*)(kb0 + kk * 32);
            const short8v fb1 = *(const short8v*)(kb1 + kk * 32);
            #pragma unroll
            for (int rf = 0; rf < 4; rf++) {
                int row = rf * 16 + lr;
                int x = (row & 7) << 4;
                short8v fa = *(short8v*)(qPc + row * 256 + ((kk * 64 + lq * 16) ^ x));
                l[rf][0] = MFMA(fa, fb0, l[rf][0]);
                l[rf][1] = MFMA(fa, fb1, l[rf][1]);
            }
        }
        #pragma unroll
        for (int rf = 0; rf < 4; rf++)
            #pragma unroll
            for (int r = 0; r < 4; r++) {
                int row = rf * 16 + lq * 4 + r;
                int x = (row & 7) << 4;
                *(float*)(SH + row * 512 + (((w * 32 + lr) * 4) ^ x))      = l[rf][0][r];
                *(float*)(SH + row * 512 + (((w * 32 + 16 + lr) * 4) ^ x)) = l[rf][1][r];
            }
    }
    __syncthreads();   // B2: logits visible

    // ================= phase 3: masked softmax (4 threads/token, 32 m each) =================
    {
        int t = tid >> 2, sub = tid & 3;
        int nv = nvis[b * SEQ + s0 + t];
        int x = (t & 7) << 4;
        float pv[32];
        #pragma unroll
        for (int u = 0; u < 8; u++) {
            float4 v = *(const float4*)(SH + t * 512 + ((sub * 128 + u * 16) ^ x));
            pv[u * 4]     = v.x; pv[u * 4 + 1] = v.y;
            pv[u * 4 + 2] = v.z; pv[u * 4 + 3] = v.w;
        }
        int base_m = sub * 32;
        float mx = -3.0e38f;
        #pragma unroll
        for (int i = 0; i < 32; i++)
            mx = (base_m + i < nv) ? fmaxf(mx, pv[i]) : mx;
        mx = fmaxf(mx, __shfl_xor(mx, 1));
        mx = fmaxf(mx, __shfl_xor(mx, 2));
        float sum = 0.f;
        #pragma unroll
        for (int i = 0; i < 32; i++) {
            float e = (base_m + i < nv) ? __expf(pv[i] - mx) : 0.f;
            pv[i] = e;
            sum += e;
        }
        sum += __shfl_xor(sum, 1);
        sum += __shfl_xor(sum, 2);
        float inv = (nv > 0) ? 1.0f / sum : 0.f;

        __syncthreads();   // B3: all lg reads done; region becomes pP/od

        #pragma unroll
        for (int u = 0; u < 4; u++) {
            short8v p;
            #pragma unroll
            for (int i = 0; i < 8; i++) p[i] = f2b(pv[u * 8 + i] * inv);
            *(short8v*)(pPc + t * 256 + ((sub * 64 + u * 16) ^ x)) = p;
        }
    }
    __syncthreads();   // B4: P visible

    // ================= phase 4: od = P @ V =================
    {
        f32x4 o[4][2];
        #pragma unroll
        for (int rf = 0; rf < 4; rf++) { o[rf][0] = zero; o[rf][1] = zero; }
        const short* vb0 = vT_bf + ((size_t)b << 14) + (w * 32 + lr) * 128 + lq * 8;
        const short* vb1 = vb0 + 16 * 128;
        #pragma unroll
        for (int kk = 0; kk < 4; kk++) {
            const short8v fb0 = *(const short8v*)(vb0 + kk * 32);
            const short8v fb1 = *(const short8v*)(vb1 + kk * 32);
            #pragma unroll
            for (int rf = 0; rf < 4; rf++) {
                int row = rf * 16 + lr;
                int x = (row & 7) << 4;
                short8v fa = *(short8v*)(pPc + row * 256 + ((kk * 64 + lq * 16) ^ x));
                o[rf][0] = MFMA(fa, fb0, o[rf][0]);
                o[rf][1] = MFMA(fa, fb1, o[rf][1]);
            }
        }
        int d0 = w * 32 + lr;
        #pragma unroll
        for (int rf = 0; rf < 4; rf++)
            #pragma unroll
            for (int r = 0; r < 4; r++) {
                int row = rf * 16 + lq * 4 + r;
                int x = (row & 7) << 4;
                *(short*)(odc + row * 256 + ((d0 * 2) ^ x))        = f2b(o[rf][0][r]);
                *(short*)(odc + row * 256 + (((d0 + 16) * 2) ^ x)) = f2b(o[rf][1][r]);
            }
    }
    __syncthreads();   // B5: od visible

    // ================= phase 5: out = od @ Wo + bo (wave w -> col quarter) =================
    {
        short8v af[4][4];
        #pragma unroll
        for (int rf = 0; rf < 4; rf++)
            #pragma unroll
            for (int kk = 0; kk < 4; kk++) {
                int row = rf * 16 + lr;
                int x = (row & 7) << 4;
                af[rf][kk] = *(short8v*)(odc + row * 256 + ((kk * 64 + lq * 16) ^ x));
            }
        #pragma unroll
        for (int grp = 0; grp < 4; grp++) {
            int colbase = w * 256 + grp * 64;
            f32x4 ac[4][4];
            #pragma unroll
            for (int rf = 0; rf < 4; rf++)
                #pragma unroll
                for (int cf = 0; cf < 4; cf++) ac[rf][cf] = zero;
            #pragma unroll
            for (int kk = 0; kk < 4; kk++) {
                #pragma unroll
                for (int cf = 0; cf < 4; cf++) {
                    const short8v bb = *(const short8v*)(WoT + (size_t)(colbase + cf * 16 + lr) * 128
                                                         + kk * 32 + lq * 8);
                    #pragma unroll
                    for (int rf = 0; rf < 4; rf++)
                        ac[rf][cf] = MFMA(af[rf][kk], bb, ac[rf][cf]);
                }
            }
            #pragma unroll
            for (int cf = 0; cf < 4; cf++) {
                int col = colbase + cf * 16 + lr;
                float bov = bo[col];
                #pragma unroll
                for (int rf = 0; rf < 4; rf++)
                    #pragma unroll
                    for (int r = 0; r < 4; r++)
                        out[(hrow + rf * 16 + lq * 4 + r) * EMB + col] = ac[rf][cf][r] + bov;
            }
        }
    }
}

extern "C" void kernel_launch(void* const* d_in, const int* in_sizes, int n_in,
                              void* d_out, int out_size, void* d_ws, size_t ws_size,
                              hipStream_t stream) {
    const int*   ids    = (const int*)d_in[0];
    const float* hidden = (const float*)d_in[1];
    const float* Wv     = (const float*)d_in[2];
    const float* bv     = (const float*)d_in[3];
    const float* Wq     = (const float*)d_in[4];
    const float* bq     = (const float*)d_in[5];
    const float* Wk     = (const float*)d_in[6];
    const float* bk     = (const float*)d_in[7];
    const float* Wvt    = (const float*)d_in[8];
    const float* bvt    = (const float*)d_in[9];
    const float* Wo     = (const float*)d_in[10];
    const float* bo     = (const float*)d_in[11];

    char* ws = (char*)d_ws;
    int*   pos   = (int*)ws;                                   // 4 KB
    int*   nvis  = (int*)(ws + (4 << 10));                     // 256 KB
    short* k_bf  = (short*)(ws + (260 << 10));                 // 256 KB
    short* vT_bf = (short*)(ws + (516 << 10));                 // 256 KB
    short* WqT   = (short*)(ws + (772 << 10));                 // 256 KB
    short* WoT   = (short*)(ws + (1028 << 10));                // 256 KB (total 1284 KB)

    seg_kernel<<<NB, 1024, 0, stream>>>(ids, pos, nvis);
    prep_w<<<512, 256, 0, stream>>>(Wq, Wo, WqT, WoT);
    dim3 g2(MAX_SEN, NB);
    statkv_kernel<<<g2, 128, 0, stream>>>(hidden, Wv, bv, Wk, bk, Wvt, bvt, pos, k_bf, vT_bf);
    attn_kernel<<<NB * (SEQ / 64), 256, 0, stream>>>(hidden, WqT, bq, k_bf, vT_bf, WoT, bo,
                                                     nvis, (float*)d_out);
}

// Round 7
// 258.370 us; speedup vs baseline: 1.3673x; 1.0135x over previous
//
#include <hip/hip_runtime.h>
#include <hip/hip_bf16.h>

#define MASK_ID 3
#define MAX_SEN 128
#define NB 8
#define SEQ 8192
#define EMB 1024
#define DIM 128

typedef __attribute__((ext_vector_type(8))) short short8v;   // 8 bf16
typedef __attribute__((ext_vector_type(4))) float f32x4;     // MFMA accumulator

#define MFMA(a, b, c) __builtin_amdgcn_mfma_f32_16x16x32_bf16(a, b, c, 0, 0, 0)

typedef __attribute__((address_space(1))) const void g_void;
typedef __attribute__((address_space(3))) void l_void;

// fp32 -> bf16 (round-nearest-even), raw short
__device__ __forceinline__ short f2b(float x) {
    union { float f; unsigned u; } v; v.f = x;
    unsigned r = (v.u + 0x7FFFu + ((v.u >> 16) & 1u)) >> 16;
    return (short)r;
}

__device__ __forceinline__ short8v cvt8(float4 a, float4 b) {
    short8v r;
    r[0] = f2b(a.x); r[1] = f2b(a.y); r[2] = f2b(a.z); r[3] = f2b(a.w);
    r[4] = f2b(b.x); r[5] = f2b(b.y); r[6] = f2b(b.z); r[7] = f2b(b.w);
    return r;
}

// ---------------- Kernel 1: per-row scan -> mask positions + nvis ----------------
__global__ __launch_bounds__(1024) void seg_kernel(const int* __restrict__ ids,
                                                   int* __restrict__ pos,
                                                   int* __restrict__ nvis) {
    int b = blockIdx.x;
    int tid = threadIdx.x;
    __shared__ int sc[1024];
    __shared__ int sc2[1024];
    const int PER = SEQ / 1024;  // 8
    int base = b * SEQ + tid * PER;

    int ids_l[PER];
    int cnt = 0;
    #pragma unroll
    for (int j = 0; j < PER; j++) {
        ids_l[j] = ids[base + j];
        cnt += (ids_l[j] == MASK_ID) ? 1 : 0;
    }
    if (tid < MAX_SEN) pos[b * MAX_SEN + tid] = -1;
    sc[tid] = cnt;
    __syncthreads();

    int* src = sc;
    int* dst = sc2;
    for (int off = 1; off < 1024; off <<= 1) {
        int v = src[tid];
        if (tid >= off) v += src[tid - off];
        dst[tid] = v;
        __syncthreads();
        int* t = src; src = dst; dst = t;
    }
    int incl = src[tid];
    int run = incl - cnt;  // exclusive prefix

    #pragma unroll
    for (int j = 0; j < PER; j++) {
        if (ids_l[j] == MASK_ID) {
            run++;
            if (run <= MAX_SEN) pos[b * MAX_SEN + run - 1] = tid * PER + j;
        }
        int nv = run; if (nv > MAX_SEN) nv = MAX_SEN;
        nvis[base + j] = nv;
    }
}

// ---------------- Kernel 2: transpose+convert weights to bf16 ----------------
__global__ __launch_bounds__(256) void prep_w(const float* __restrict__ Wq,
                                              const float* __restrict__ Wo,
                                              short* __restrict__ WqT,
                                              short* __restrict__ WoT) {
    int idx = blockIdx.x * 256 + threadIdx.x;      // 0 .. 131071
    int d = idx >> 10, e = idx & 1023;
    WqT[idx] = f2b(Wq[e * DIM + d]);
    int e2 = idx >> 7, d2 = idx & 127;
    WoT[idx] = f2b(Wo[d2 * EMB + e2]);
}

// ---------------- Kernel 3: fused static+kv: k_bf[m][d], vT_bf[d][m] ----------------
__global__ __launch_bounds__(128) void statkv_kernel(const float* __restrict__ hidden,
                                                     const float* __restrict__ Wv, const float* __restrict__ bv,
                                                     const float* __restrict__ Wk, const float* __restrict__ bk,
                                                     const float* __restrict__ Wvt, const float* __restrict__ bvt,
                                                     const int* __restrict__ pos,
                                                     short* __restrict__ k_bf, short* __restrict__ vT_bf) {
    int m = blockIdx.x, b = blockIdx.y;
    int d = threadIdx.x;
    __shared__ float h[EMB];
    __shared__ float srow[DIM];
    int p = pos[b * MAX_SEN + m];   // uniform across block
    float acc = bv[d];
    if (p >= 0) {
        const float* hp = hidden + ((size_t)b * SEQ + p) * EMB;
        for (int e = d; e < EMB; e += 128) h[e] = hp[e];
        __syncthreads();
        float a0 = 0.f, a1 = 0.f, a2 = 0.f, a3 = 0.f;
        for (int e = 0; e < EMB; e += 4) {
            a0 += h[e]     * Wv[e * DIM + d];
            a1 += h[e + 1] * Wv[(e + 1) * DIM + d];
            a2 += h[e + 2] * Wv[(e + 2) * DIM + d];
            a3 += h[e + 3] * Wv[(e + 3) * DIM + d];
        }
        acc += (a0 + a1) + (a2 + a3);
    }
    srow[d] = acc;
    __syncthreads();
    float k0 = 0.f, k1 = 0.f, v0 = 0.f, v1 = 0.f;
    for (int e = 0; e < DIM; e += 2) {
        float s0 = srow[e], s1 = srow[e + 1];
        k0 += s0 * Wk[e * DIM + d];
        k1 += s1 * Wk[(e + 1) * DIM + d];
        v0 += s0 * Wvt[e * DIM + d];
        v1 += s1 * Wvt[(e + 1) * DIM + d];
    }
    k_bf[((size_t)b * MAX_SEN + m) * DIM + d] = f2b(bk[d] + k0 + k1);
    vT_bf[((size_t)b * DIM + d) * MAX_SEN + m] = f2b(bvt[d] + v0 + v1);
}

// ---------------- Kernel 4: fused MFMA attention, 64 tokens/block ----------------
// Phase 1: T3/T4 counted-vmcnt pipeline, 3 LDS buffers, depth ~2.5 chunks.
// Issue schedule per iter c: wait vmcnt(12) -> s_barrier -> compute(c) ->
// s_barrier -> load W(c+2) (regs) -> glds(c+3). vmcnt NEVER drains to 0 in
// the main loop; WqT loads sit OLDER than the next glds group in the queue.
__global__ __launch_bounds__(256, 3) void attn_kernel(
    const float* __restrict__ hidden,
    const short* __restrict__ WqT, const float* __restrict__ bq,
    const short* __restrict__ k_bf, const short* __restrict__ vT_bf,
    const short* __restrict__ WoT, const float* __restrict__ bo,
    const int* __restrict__ nvis,
    float* __restrict__ out) {
    // XCD swizzle: 1024 blocks = 8 XCDs x 128; XCD x owns batch x
    int wg = (blockIdx.x & 7) * 128 + (blockIdx.x >> 3);
    int b  = wg >> 7;
    int s0 = (wg & 127) * 64;
    int tid = threadIdx.x;
    int lane = tid & 63;
    int w  = tid >> 6;             // wave 0..3
    int lr = lane & 15;
    int lq = lane >> 4;            // quarter 0..3

    // LDS 48KB: ph1: 3 A-buffers (3x16K). ph2-3: lg = SH[0,32K). ph3-5:
    // pP = SH[0,16K), od = SH[16K,32K). qP = SH[32K,48K) (written after last
    // compute; physical slot of buf2 is dead by then).
    __shared__ __align__(16) char SH[49152];
    char* pPc = SH;
    char* odc = SH + 16384;
    char* qPc = SH + 32768;

    const size_t hrow = (size_t)b * SEQ + s0;
    const char* hbytes = (const char*)(hidden + hrow * EMB);
    f32x4 zero = {0.f, 0.f, 0.f, 0.f};

    f32x4 acc[4][2];
    #pragma unroll
    for (int rf = 0; rf < 4; rf++) { acc[rf][0] = zero; acc[rf][1] = zero; }

#define WAITV(N) do { asm volatile("s_waitcnt vmcnt(" #N ")" ::: "memory"); \
                      __builtin_amdgcn_sched_barrier(0); } while (0)

#define STAGE(C, B) do { \
    int lsub = lane >> 4; \
    int blin = (lane & 15) << 4; \
    _Pragma("unroll") \
    for (int j = 0; j < 4; j++) { \
        int row = w * 16 + j * 4 + lsub; \
        const char* sp = hbytes + (size_t)row * 4096 + (C) * 256 + (blin ^ ((row & 7) << 4)); \
        __builtin_amdgcn_global_load_lds((g_void*)sp, (l_void*)((B) + w * 4096 + j * 1024), 16, 0, 0); \
    } } while (0)

#define LOAD_W(C, W) do { \
    const short* basep = WqT + (size_t)(w * 32 + lr) * 1024 + (C) * 64 + lq * 8; \
    W[0] = *(const short8v*)(basep); \
    W[1] = *(const short8v*)(basep + 32); \
    W[2] = *(const short8v*)(basep + 16 * 1024); \
    W[3] = *(const short8v*)(basep + 16 * 1024 + 32); } while (0)

#define COMPUTE(B, W) do { \
    _Pragma("unroll") \
    for (int ks = 0; ks < 2; ks++) { \
        _Pragma("unroll") \
        for (int rf = 0; rf < 4; rf++) { \
            int row = rf * 16 + lr; \
            int x = (row & 7) << 4; \
            int kb = ks * 128 + lq * 32; \
            float4 f0 = *(const float4*)((B) + row * 256 + (kb ^ x)); \
            float4 f1 = *(const float4*)((B) + row * 256 + ((kb + 16) ^ x)); \
            short8v fa = cvt8(f0, f1); \
            acc[rf][0] = MFMA(fa, W[ks], acc[rf][0]); \
            acc[rf][1] = MFMA(fa, W[2 + ks], acc[rf][1]); \
        } } } while (0)

#define ROTATE() do { char* tt = b0; b0 = b1; b1 = b2; b2 = tt; } while (0)

    // ================= phase 1: q = (H @ Wq + bq) * scale =================
    {
        char* b0 = SH;
        char* b1 = SH + 16384;
        char* b2 = SH + 32768;
        short8v Wa[4], Wb[4];

        // prologue — queue (oldest->): g0, W0, g1, W1, g2  (20 outstanding)
        STAGE(0, b0);
        LOAD_W(0, Wa);
        STAGE(1, b1);
        LOAD_W(1, Wb);
        STAGE(2, b2);

        // steady state: c = 0..11 (even->Wa, odd->Wb)
        for (int c = 0; c < 12; c += 2) {
            WAITV(12);                       // g(c)+W(c) done; leaves g,W,g = 12
            __builtin_amdgcn_s_barrier();
            __builtin_amdgcn_sched_barrier(0);
            COMPUTE(b0, Wa);
            __builtin_amdgcn_s_barrier();
            __builtin_amdgcn_sched_barrier(0);
            LOAD_W(c + 2, Wa);               // W older than next glds group
            STAGE(c + 3, b0);
            ROTATE();

            WAITV(12);
            __builtin_amdgcn_s_barrier();
            __builtin_amdgcn_sched_barrier(0);
            COMPUTE(b0, Wb);
            __builtin_amdgcn_s_barrier();
            __builtin_amdgcn_sched_barrier(0);
            LOAD_W(c + 3, Wb);
            STAGE(c + 4, b0);
            ROTATE();
        }
        // c = 12: last STAGE (chunk 15)
        WAITV(12);
        __builtin_amdgcn_s_barrier();
        __builtin_amdgcn_sched_barrier(0);
        COMPUTE(b0, Wa);
        __builtin_amdgcn_s_barrier();
        __builtin_amdgcn_sched_barrier(0);
        LOAD_W(14, Wa);
        STAGE(15, b0);
        ROTATE();
        // c = 13: last LOAD_W (chunk 15)
        WAITV(12);
        __builtin_amdgcn_s_barrier();
        __builtin_amdgcn_sched_barrier(0);
        COMPUTE(b0, Wb);
        __builtin_amdgcn_s_barrier();
        __builtin_amdgcn_sched_barrier(0);
        LOAD_W(15, Wb);
        ROTATE();
        // c = 14: queue = W14,g15,W15 (12) -> need W14: wait 8
        WAITV(8);
        __builtin_amdgcn_s_barrier();
        __builtin_amdgcn_sched_barrier(0);
        COMPUTE(b0, Wa);
        __builtin_amdgcn_s_barrier();
        __builtin_amdgcn_sched_barrier(0);
        ROTATE();
        // c = 15: queue = g15,W15 (8) -> need both: wait 0
        WAITV(0);
        __builtin_amdgcn_s_barrier();
        __builtin_amdgcn_sched_barrier(0);
        COMPUTE(b0, Wb);
    }
    {
        const float scale = 0.08838834764831845f;  // 128^-0.5
        int d0 = w * 32 + lr;
        float bq0 = bq[d0], bq1 = bq[d0 + 16];
        #pragma unroll
        for (int rf = 0; rf < 4; rf++)
            #pragma unroll
            for (int r = 0; r < 4; r++) {
                int row = rf * 16 + lq * 4 + r;
                int x = (row & 7) << 4;
                *(short*)(qPc + row * 256 + ((d0 * 2) ^ x))        = f2b((acc[rf][0][r] + bq0) * scale);
                *(short*)(qPc + row * 256 + (((d0 + 16) * 2) ^ x)) = f2b((acc[rf][1][r] + bq1) * scale);
            }
    }
    __syncthreads();   // B1: q visible; A-bufs dead -> lg region live

    // ================= phase 2: logits = q @ K^T (lg = 64 rows x 512B, swz) =================
    {
        f32x4 l[4][2];
        #pragma unroll
        for (int rf = 0; rf < 4; rf++) { l[rf][0] = zero; l[rf][1] = zero; }
        const short* kb0 = k_bf + ((size_t)b << 14) + (w * 32 + lr) * 128 + lq * 8;
        const short* kb1 = kb0 + 16 * 128;
        #pragma unroll
        for (int kk = 0; kk < 4; kk++) {
            const short8v fb0 = *(const short8v*)(kb0 + kk * 32);
            const short8v fb1 = *(const short8v*)(kb1 + kk * 32);
            #pragma unroll
            for (int rf = 0; rf < 4; rf++) {
                int row = rf * 16 + lr;
                int x = (row & 7) << 4;
                short8v fa = *(short8v*)(qPc + row * 256 + ((kk * 64 + lq * 16) ^ x));
                l[rf][0] = MFMA(fa, fb0, l[rf][0]);
                l[rf][1] = MFMA(fa, fb1, l[rf][1]);
            }
        }
        #pragma unroll
        for (int rf = 0; rf < 4; rf++)
            #pragma unroll
            for (int r = 0; r < 4; r++) {
                int row = rf * 16 + lq * 4 + r;
                int x = (row & 7) << 4;
                *(float*)(SH + row * 512 + (((w * 32 + lr) * 4) ^ x))      = l[rf][0][r];
                *(float*)(SH + row * 512 + (((w * 32 + 16 + lr) * 4) ^ x)) = l[rf][1][r];
            }
    }
    __syncthreads();   // B2: logits visible

    // ================= phase 3: masked softmax (4 threads/token, 32 m each) =================
    {
        int t = tid >> 2, sub = tid & 3;
        int nv = nvis[b * SEQ + s0 + t];
        int x = (t & 7) << 4;
        float pv[32];
        #pragma unroll
        for (int u = 0; u < 8; u++) {
            float4 v = *(const float4*)(SH + t * 512 + ((sub * 128 + u * 16) ^ x));
            pv[u * 4]     = v.x; pv[u * 4 + 1] = v.y;
            pv[u * 4 + 2] = v.z; pv[u * 4 + 3] = v.w;
        }
        int base_m = sub * 32;
        float mx = -3.0e38f;
        #pragma unroll
        for (int i = 0; i < 32; i++)
            mx = (base_m + i < nv) ? fmaxf(mx, pv[i]) : mx;
        mx = fmaxf(mx, __shfl_xor(mx, 1));
        mx = fmaxf(mx, __shfl_xor(mx, 2));
        float sum = 0.f;
        #pragma unroll
        for (int i = 0; i < 32; i++) {
            float e = (base_m + i < nv) ? __expf(pv[i] - mx) : 0.f;
            pv[i] = e;
            sum += e;
        }
        sum += __shfl_xor(sum, 1);
        sum += __shfl_xor(sum, 2);
        float inv = (nv > 0) ? 1.0f / sum : 0.f;

        __syncthreads();   // B3: all lg reads done; region becomes pP/od

        #pragma unroll
        for (int u = 0; u < 4; u++) {
            short8v p;
            #pragma unroll
            for (int i = 0; i < 8; i++) p[i] = f2b(pv[u * 8 + i] * inv);
            *(short8v*)(pPc + t * 256 + ((sub * 64 + u * 16) ^ x)) = p;
        }
    }
    __syncthreads();   // B4: P visible

    // ================= phase 4: od = P @ V =================
    {
        f32x4 o[4][2];
        #pragma unroll
        for (int rf = 0; rf < 4; rf++) { o[rf][0] = zero; o[rf][1] = zero; }
        const short* vb0 = vT_bf + ((size_t)b << 14) + (w * 32 + lr) * 128 + lq * 8;
        const short* vb1 = vb0 + 16 * 128;
        #pragma unroll
        for (int kk = 0; kk < 4; kk++) {
            const short8v fb0 = *(const short8v*)(vb0 + kk * 32);
            const short8v fb1 = *(const short8v*)(vb1 + kk * 32);
            #pragma unroll
            for (int rf = 0; rf < 4; rf++) {
                int row = rf * 16 + lr;
                int x = (row & 7) << 4;
                short8v fa = *(short8v*)(pPc + row * 256 + ((kk * 64 + lq * 16) ^ x));
                o[rf][0] = MFMA(fa, fb0, o[rf][0]);
                o[rf][1] = MFMA(fa, fb1, o[rf][1]);
            }
        }
        int d0 = w * 32 + lr;
        #pragma unroll
        for (int rf = 0; rf < 4; rf++)
            #pragma unroll
            for (int r = 0; r < 4; r++) {
                int row = rf * 16 + lq * 4 + r;
                int x = (row & 7) << 4;
                *(short*)(odc + row * 256 + ((d0 * 2) ^ x))        = f2b(o[rf][0][r]);
                *(short*)(odc + row * 256 + (((d0 + 16) * 2) ^ x)) = f2b(o[rf][1][r]);
            }
    }
    __syncthreads();   // B5: od visible

    // ================= phase 5: out = od @ Wo + bo (wave w -> col quarter) =================
    {
        short8v af[4][4];
        #pragma unroll
        for (int rf = 0; rf < 4; rf++)
            #pragma unroll
            for (int kk = 0; kk < 4; kk++) {
                int row = rf * 16 + lr;
                int x = (row & 7) << 4;
                af[rf][kk] = *(short8v*)(odc + row * 256 + ((kk * 64 + lq * 16) ^ x));
            }
        #pragma unroll
        for (int grp = 0; grp < 4; grp++) {
            int colbase = w * 256 + grp * 64;
            f32x4 ac[4][4];
            #pragma unroll
            for (int rf = 0; rf < 4; rf++)
                #pragma unroll
                for (int cf = 0; cf < 4; cf++) ac[rf][cf] = zero;
            #pragma unroll
            for (int kk = 0; kk < 4; kk++) {
                #pragma unroll
                for (int cf = 0; cf < 4; cf++) {
                    const short8v bb = *(const short8v*)(WoT + (size_t)(colbase + cf * 16 + lr) * 128
                                                         + kk * 32 + lq * 8);
                    #pragma unroll
                    for (int rf = 0; rf < 4; rf++)
                        ac[rf][cf] = MFMA(af[rf][kk], bb, ac[rf][cf]);
                }
            }
            #pragma unroll
            for (int cf = 0; cf < 4; cf++) {
                int col = colbase + cf * 16 + lr;
                float bov = bo[col];
                #pragma unroll
                for (int rf = 0; rf < 4; rf++)
                    #pragma unroll
                    for (int r = 0; r < 4; r++)
                        out[(hrow + rf * 16 + lq * 4 + r) * EMB + col] = ac[rf][cf][r] + bov;
            }
        }
    }
}

extern "C" void kernel_launch(void* const* d_in, const int* in_sizes, int n_in,
                              void* d_out, int out_size, void* d_ws, size_t ws_size,
                              hipStream_t stream) {
    const int*   ids    = (const int*)d_in[0];
    const float* hidden = (const float*)d_in[1];
    const float* Wv     = (const float*)d_in[2];
    const float* bv     = (const float*)d_in[3];
    const float* Wq     = (const float*)d_in[4];
    const float* bq     = (const float*)d_in[5];
    const float* Wk     = (const float*)d_in[6];
    const float* bk     = (const float*)d_in[7];
    const float* Wvt    = (const float*)d_in[8];
    const float* bvt    = (const float*)d_in[9];
    const float* Wo     = (const float*)d_in[10];
    const float* bo     = (const float*)d_in[11];

    char* ws = (char*)d_ws;
    int*   pos   = (int*)ws;                                   // 4 KB
    int*   nvis  = (int*)(ws + (4 << 10));                     // 256 KB
    short* k_bf  = (short*)(ws + (260 << 10));                 // 256 KB
    short* vT_bf = (short*)(ws + (516 << 10));                 // 256 KB
    short* WqT   = (short*)(ws + (772 << 10));                 // 256 KB
    short* WoT   = (short*)(ws + (1028 << 10));                // 256 KB (total 1284 KB)

    seg_kernel<<<NB, 1024, 0, stream>>>(ids, pos, nvis);
    prep_w<<<512, 256, 0, stream>>>(Wq, Wo, WqT, WoT);
    dim3 g2(MAX_SEN, NB);
    statkv_kernel<<<g2, 128, 0, stream>>>(hidden, Wv, bv, Wk, bk, Wvt, bvt, pos, k_bf, vT_bf);
    attn_kernel<<<NB * (SEQ / 64), 256, 0, stream>>>(hidden, WqT, bq, k_bf, vT_bf, WoT, bo,
                                                     nvis, (float*)d_out);
}